// Round 1
// 120.917 us; speedup vs baseline: 1.0065x; 1.0065x over previous
//
#include <hip/hip_runtime.h>

#define D 64
#define NK 1024
#define QTOTAL 65536
#define NELEM (QTOTAL * D)
#define LOSS_OFF 4194304
#define IDX_OUT_OFF 4194305
#define CAPQ 16384
#define MARGIN 2.0e-3f

typedef float f32x16 __attribute__((ext_vector_type(16)));
typedef short bf16x8 __attribute__((ext_vector_type(8)));
typedef float f32x4 __attribute__((ext_vector_type(4)));
typedef float f32x2 __attribute__((ext_vector_type(2)));
typedef unsigned int u32;
typedef unsigned short ushort_t;

// ---- ws layout (bytes) ----
#define WS_E2   0          // 1024 f32
#define WS_B    4096       // 256 KB permuted bf16 codebook: [tile][H0|H1|M0|M1][lane][8]
#define WS_CNT  266240     // u32 (+pad)
#define WS_LIST 266496     // 16384 i32
#define WS_NEED 332032

__device__ __forceinline__ ushort_t f2bf(float f) {
    u32 u = __float_as_uint(f);
    return (ushort_t)((u + 0x7FFFu + ((u >> 16) & 1u)) >> 16);
}
__device__ __forceinline__ float bf2f(ushort_t h) {
    return __uint_as_float(((u32)h) << 16);
}

// ---------------- K0: permuted bf16 hi/mid split; e2; zero loss+cnt ---------
// B[t*4096B + buf*1024B + lane*16B + j*2B]: coalesced MFMA-fragment order.
__global__ __launch_bounds__(256) void vqk0(const float* __restrict__ emb,
                                            u32* __restrict__ b32,
                                            float* __restrict__ e2, u32* __restrict__ cnt,
                                            float* __restrict__ out) {
    int gid = blockIdx.x * 256 + threadIdx.x;   // 128 blocks -> 32768 threads
    int c = gid >> 5;
    int d = (gid & 31) * 2;                     // even dim; pair (d, d+1) same group
    float2 v = ((const float2*)emb)[gid];       // coalesced read
    ushort_t h0 = f2bf(v.x), h1 = f2bf(v.y);
    ushort_t m0 = f2bf(v.x - bf2f(h0)), m1 = f2bf(v.y - bf2f(h1));
    int t = c >> 4, row = c & 15;
    int g = (d & 31) >> 3;
    int bh = (d < 32) ? 0 : 1;
    int lane = g * 16 + row;
    int u = t * 1024 + lane * 4 + ((d & 7) >> 1);   // u32 units within tile block
    b32[u + bh * 256]       = (u32)h0 | ((u32)h1 << 16);
    b32[u + (bh + 2) * 256] = (u32)m0 | ((u32)m1 << 16);
    if (gid < NK) {                             // exact f32 |e|^2 (R3 order)
        const float4* e4 = (const float4*)(emb + (long)gid * D);
        float s = 0.f;
#pragma unroll
        for (int i = 0; i < D / 4; ++i) {
            float4 w = e4[i];
            s += w.x * w.x + w.y * w.y + w.z * w.z + w.w * w.w;
        }
        e2[gid] = s;
    }
    if (gid == 0) { out[LOSS_OFF] = 0.0f; *cnt = 0; }
}

// One 16-code tile vs the wave's single 16-query sub-tile.
// e2l holds 0.5*|e|^2 (pre-scaled at fill; exact).
#define COMPUTE_TILE(T, BH0, BH1, BM0, BM1) do {                               \
    const int c_ = (T) * 16 + row;                                             \
    const float h_ = e2l[c_];                                                  \
    f32x4 acc = {0.f, 0.f, 0.f, 0.f};                                          \
    acc = __builtin_amdgcn_mfma_f32_16x16x32_bf16(ah[0], BM0, acc, 0, 0, 0);   \
    acc = __builtin_amdgcn_mfma_f32_16x16x32_bf16(am[0], BH0, acc, 0, 0, 0);   \
    acc = __builtin_amdgcn_mfma_f32_16x16x32_bf16(ah[0], BH0, acc, 0, 0, 0);   \
    acc = __builtin_amdgcn_mfma_f32_16x16x32_bf16(ah[1], BM1, acc, 0, 0, 0);   \
    acc = __builtin_amdgcn_mfma_f32_16x16x32_bf16(am[1], BH1, acc, 0, 0, 0);   \
    acc = __builtin_amdgcn_mfma_f32_16x16x32_bf16(ah[1], BH1, acc, 0, 0, 0);   \
    _Pragma("unroll")                                                          \
    for (int r_ = 0; r_ < 4; ++r_) {                                           \
        float sd_ = h_ - acc[r_];                                              \
        float ns2_ = fminf(fmaxf(sd_, s1v[r_]), s2v[r_]);   /* med3 */         \
        bool lt_ = sd_ < s1v[r_];                                              \
        i1v[r_] = lt_ ? c_ : i1v[r_];                                          \
        s1v[r_] = fminf(sd_, s1v[r_]);                                         \
        s2v[r_] = ns2_;                                                        \
    }                                                                          \
} while (0)

// Read tile frag (4 x bf16x8) for local tile tt from LDS stage buffer.
#define LDS_FRAG(SB, TT, H0, H1, M0, M1) do {                                  \
    const ushort_t* p_ = (SB) + (TT) * 2048 + l * 8;                           \
    H0 = *(const bf16x8*)(p_);                                                 \
    H1 = *(const bf16x8*)(p_ + 512);                                           \
    M0 = *(const bf16x8*)(p_ + 1024);                                          \
    M1 = *(const bf16x8*)(p_ + 1536);                                          \
} while (0)

// ---------------- K1: LDS-staged coarse MFMA top-2 + streaming epilogue -----
// 512 blocks x 512 thr (2 blocks/CU, 4 waves/SIMD = 2x prior occupancy).
// Wave owns 16 queries (one 16x16 sub-tile): same total MFMA work as before
// but twice the independent MFMA dep-chains per SIMD to hide latency.
// Codebook staged through LDS in 32-KB chunks (8 tiles), double-buffered:
// global loads for chunk c+1 issue at top of chunk c (latency hidden under
// ~3700 cyc of compute, drained only at the ds_write before the barrier).
// Hot loop reads conflict-free ds_read_b128 with one-tile register prefetch.
__global__ __launch_bounds__(512, 4) void vqk1(const float* __restrict__ x,
                                               const ushort_t* __restrict__ B,
                                               const float* __restrict__ e2g,
                                               const float* __restrict__ emb,
                                               u32* __restrict__ cnt,
                                               int* __restrict__ list,
                                               float* __restrict__ out) {
    __shared__ f32x4 stage[2][2048];  // 2 x 32 KB chunk buffers
    __shared__ float e2l[NK];         // 4 KB (holds 0.5*|e|^2)
    __shared__ int   idx_l[128];
    __shared__ float lred[8];

    const int tid = threadIdx.x;
    const int l = tid & 63;
    const int w = tid >> 6;          // 8 waves
    const int qbase = blockIdx.x * 128;
    const int wb = qbase + w * 16;   // wave's first query
    const int row = l & 15;
    const int g = l >> 4;
    const int koff = g * 8;

    {   // e2 -> LDS, pre-scaled by 0.5 (exact)
        f32x2 t = ((const f32x2*)e2g)[tid];
        ((f32x2*)e2l)[tid] = t * 0.5f;
    }

    // Split this wave's 16 queries into bf16 hi/mid A-frags in-register.
    bf16x8 ah[2], am[2];
    {
        const float* xr = x + (long)(wb + row) * D + koff;
#pragma unroll
        for (int half = 0; half < 2; ++half) {
            float4 p0 = ((const float4*)(xr + half * 32))[0];
            float4 p1 = ((const float4*)(xr + half * 32))[1];
            float v[8] = {p0.x, p0.y, p0.z, p0.w, p1.x, p1.y, p1.z, p1.w};
#pragma unroll
            for (int i = 0; i < 8; ++i) {
                ushort_t hs = f2bf(v[i]);
                ushort_t ms = f2bf(v[i] - bf2f(hs));
                ah[half][i] = (short)hs;
                am[half][i] = (short)ms;
            }
        }
    }

    float s1v[4], s2v[4];
    int i1v[4];
#pragma unroll
    for (int i = 0; i < 4; ++i) { s1v[i] = 3.4e38f; s2v[i] = 3.4e38f; i1v[i] = 0; }

    const f32x4* gB = (const f32x4*)B;   // 16-B units; tile = 256 units

    // ---- prologue: stage chunk 0 (8 tiles = 2048 units, 4 per thread) ----
    {
        f32x4 st0[4];
#pragma unroll
        for (int tt = 0; tt < 4; ++tt) st0[tt] = gB[tt * 512 + tid];
#pragma unroll
        for (int tt = 0; tt < 4; ++tt) stage[0][tt * 512 + tid] = st0[tt];
    }
    __syncthreads();

    // ---- main scan: 8 chunks x 8 tiles ----
#pragma unroll 1
    for (int c = 0; c < 8; ++c) {
        const int cb = c & 1;
        const ushort_t* sb = (const ushort_t*)&stage[cb][0];

        // issue global loads for chunk c+1 (consumed ~3700 cyc later)
        f32x4 st[4];
        if (c < 7) {
#pragma unroll
            for (int tt = 0; tt < 4; ++tt)
                st[tt] = gB[(c + 1) * 2048 + tt * 512 + tid];
        }

        // compute 8 tiles with one-tile-ahead LDS register prefetch
        bf16x8 bh0, bh1, bm0, bm1, nh0, nh1, nm0, nm1;
        LDS_FRAG(sb, 0, bh0, bh1, bm0, bm1);
#pragma unroll
        for (int tt = 0; tt < 8; ++tt) {
            if (tt < 7) LDS_FRAG(sb, tt + 1, nh0, nh1, nm0, nm1);
            COMPUTE_TILE(c * 8 + tt, bh0, bh1, bm0, bm1);
            bh0 = nh0; bh1 = nh1; bm0 = nm0; bm1 = nm1;
        }

        // write staged chunk into the other buffer, then barrier
        if (c < 7) {
#pragma unroll
            for (int tt = 0; tt < 4; ++tt)
                stage[cb ^ 1][tt * 512 + tid] = st[tt];
        }
        __syncthreads();
    }

    // merge top-2 across the 16 code-columns; lowest index wins exact ties.
#pragma unroll
    for (int d = 1; d < 16; d <<= 1) {
#pragma unroll
        for (int sl = 0; sl < 4; ++sl) {
            float os1 = __shfl_xor(s1v[sl], d, 64);
            float os2 = __shfl_xor(s2v[sl], d, 64);
            int   oi1 = __shfl_xor(i1v[sl], d, 64);
            float hi = s1v[sl] > os1 ? s1v[sl] : os1;
            float lo2 = s2v[sl] < os2 ? s2v[sl] : os2;
            int ni = (os1 < s1v[sl]) ? oi1
                   : ((os1 == s1v[sl] && oi1 < i1v[sl]) ? oi1 : i1v[sl]);
            s1v[sl] = s1v[sl] < os1 ? s1v[sl] : os1;
            s2v[sl] = hi < lo2 ? hi : lo2;
            i1v[sl] = ni;
        }
    }

    if (row == 0) {
#pragma unroll
        for (int sl = 0; sl < 4; ++sl) {
            int ql = w * 16 + g * 4 + sl;
            idx_l[ql] = i1v[sl];
            if (s2v[sl] - s1v[sl] <= MARGIN) {
                u32 p = atomicAdd(cnt, 1u);
                if (p < CAPQ) list[p] = qbase + ql;
            }
        }
    }
    __syncthreads();

    // ---- streaming epilogue: idx write, gather quantized, loss partial ----
    if (l < 16) out[IDX_OUT_OFF + wb + l] = (float)idx_l[w * 16 + l];

    const f32x4* x4 = (const f32x4*)(x + (long)wb * D);
    const f32x4* e4 = (const f32x4*)emb;
    f32x4* o4 = (f32x4*)(out + (long)wb * D);
    float ls = 0.f;
#pragma unroll 1
    for (int k = 0; k < 4; ++k) {
        int j = l + 64 * k;                      // float4 slot in wave's 4 KB
        int ql = j >> 4;                         // local query for this slot
        int col = j & 15;                        // float4 column within row
        int idx = idx_l[w * 16 + ql];
        f32x4 xv = x4[j];
        f32x4 ev = e4[idx * 16 + col];           // 16 lanes same row: coalesced
        o4[j] = ev;
        f32x4 dd = ev - xv;
        ls += dd[0] * dd[0] + dd[1] * dd[1] + dd[2] * dd[2] + dd[3] * dd[3];
    }
#pragma unroll
    for (int offr = 32; offr > 0; offr >>= 1) ls += __shfl_down(ls, offr, 64);
    if (l == 0) lred[w] = ls;
    __syncthreads();
    if (tid == 0) {
        float t = 0.f;
#pragma unroll
        for (int i = 0; i < 8; ++i) t += lred[i];
        atomicAdd(&out[LOSS_OFF], t * (0.25f / (float)NELEM));
    }
}

// ---------------- K2: exact rescue fix-up (one wave per flagged query) ------
__global__ __launch_bounds__(64) void vqk2(const float* __restrict__ x,
                                           const float* __restrict__ emb,
                                           const float* __restrict__ e2,
                                           const int* __restrict__ list,
                                           const u32* __restrict__ cnt,
                                           float* __restrict__ out) {
    u32 n = *cnt; if (n > CAPQ) n = CAPQ;
    const int l = threadIdx.x;
    for (u32 f = blockIdx.x; f < n; f += gridDim.x) {
        int q = list[f];
        float4 xv[16];
        const float4* xp = (const float4*)(x + (long)q * D);
#pragma unroll
        for (int i = 0; i < 16; ++i) xv[i] = xp[i];
        float best = 3.4e38f; int bi = 0;
#pragma unroll 1
        for (int i = 0; i < 16; ++i) {
            int c = l * 16 + i;                  // lane covers [l*16, l*16+16)
            const float4* ep = (const float4*)(emb + (long)c * D);
            float a0 = 0.f, a1 = 0.f, a2 = 0.f, a3 = 0.f;
#pragma unroll
            for (int k = 0; k < 16; ++k) {
                float4 e = ep[k];
                a0 = fmaf(e.x, xv[k].x, a0); a1 = fmaf(e.y, xv[k].y, a1);
                a2 = fmaf(e.z, xv[k].z, a2); a3 = fmaf(e.w, xv[k].w, a3);
            }
            float s = 0.5f * e2[c] - ((a0 + a1) + (a2 + a3));
            if (s < best) { best = s; bi = c; }  // ascending c: first-min
        }
#pragma unroll
        for (int off = 32; off > 0; off >>= 1) {
            float ob = __shfl_down(best, off, 64);
            int   oi = __shfl_down(bi, off, 64);
            if (ob < best || (ob == best && oi < bi)) { best = ob; bi = oi; }
        }
        bi = __shfl(bi, 0, 64);
        int ci = (int)out[IDX_OUT_OFF + q];      // coarse pick
        if (bi != ci) {
            float xl = x[(long)q * D + l];
            float en = emb[(long)bi * D + l];
            float eo = emb[(long)ci * D + l];
            out[(long)q * D + l] = en;
            float dn = (en - xl) * (en - xl);
            float dol = (eo - xl) * (eo - xl);
            float dd = dn - dol;
#pragma unroll
            for (int off = 32; off > 0; off >>= 1) dd += __shfl_down(dd, off, 64);
            if (l == 0) {
                out[IDX_OUT_OFF + q] = (float)bi;
                atomicAdd(&out[LOSS_OFF], dd * (0.25f / (float)NELEM));
            }
        }
    }
}

// ================== R3 fallback (ws too small) ==============================
#define FDO_CHUNK(B, K) \
    aA0 = fmaf(B[0],  xA[4*K+0].x, aA0); aA1 = fmaf(B[1],  xA[4*K+0].y, aA1); \
    aA2 = fmaf(B[2],  xA[4*K+0].z, aA2); aA3 = fmaf(B[3],  xA[4*K+0].w, aA3); \
    aA0 = fmaf(B[4],  xA[4*K+1].x, aA0); aA1 = fmaf(B[5],  xA[4*K+1].y, aA1); \
    aA2 = fmaf(B[6],  xA[4*K+1].z, aA2); aA3 = fmaf(B[7],  xA[4*K+1].w, aA3); \
    aA0 = fmaf(B[8],  xA[4*K+2].x, aA0); aA1 = fmaf(B[9],  xA[4*K+2].y, aA1); \
    aA2 = fmaf(B[10], xA[4*K+2].z, aA2); aA3 = fmaf(B[11], xA[4*K+2].w, aA3); \
    aA0 = fmaf(B[12], xA[4*K+3].x, aA0); aA1 = fmaf(B[13], xA[4*K+3].y, aA1); \
    aA2 = fmaf(B[14], xA[4*K+3].z, aA2); aA3 = fmaf(B[15], xA[4*K+3].w, aA3); \
    aB0 = fmaf(B[0],  xB[4*K+0].x, aB0); aB1 = fmaf(B[1],  xB[4*K+0].y, aB1); \
    aB2 = fmaf(B[2],  xB[4*K+0].z, aB2); aB3 = fmaf(B[3],  xB[4*K+0].w, aB3); \
    aB0 = fmaf(B[4],  xB[4*K+1].x, aB0); aB1 = fmaf(B[5],  xB[4*K+1].y, aB1); \
    aB2 = fmaf(B[6],  xB[4*K+1].z, aB2); aB3 = fmaf(B[7],  xB[4*K+1].w, aB3); \
    aB0 = fmaf(B[8],  xB[4*K+2].x, aB0); aB1 = fmaf(B[9],  xB[4*K+2].y, aB1); \
    aB2 = fmaf(B[10], xB[4*K+2].z, aB2); aB3 = fmaf(B[11], xB[4*K+2].w, aB3); \
    aB0 = fmaf(B[12], xB[4*K+3].x, aB0); aB1 = fmaf(B[13], xB[4*K+3].y, aB1); \
    aB2 = fmaf(B[14], xB[4*K+3].z, aB2); aB3 = fmaf(B[15], xB[4*K+3].w, aB3);

__global__ __launch_bounds__(256) void vq_e2f(const float* __restrict__ emb,
                                              float* __restrict__ e2,
                                              float* __restrict__ out) {
    int k = blockIdx.x * blockDim.x + threadIdx.x;
    if (k == 0) out[LOSS_OFF] = 0.0f;
    if (k < NK) {
        const float4* e4 = (const float4*)(emb + k * D);
        float s = 0.f;
#pragma unroll
        for (int i = 0; i < D / 4; ++i) {
            float4 v = e4[i];
            s += v.x * v.x + v.y * v.y + v.z * v.z + v.w * v.w;
        }
        e2[k] = s;
    }
}

__global__ __launch_bounds__(256, 2) void vq_mainf(const float* __restrict__ x,
                                                   const float* __restrict__ emb,
                                                   const float* __restrict__ e2g,
                                                   float* __restrict__ out) {
    __shared__ float e2l[NK];
    __shared__ float sm_s[512];
    __shared__ int   sm_c[512];
    const int tid = threadIdx.x;
    const int l = tid & 63;
    const int w = tid >> 6;
    const int qbase = blockIdx.x * 128;
    ((float4*)e2l)[tid] = ((const float4*)e2g)[tid];
    float4 xA[16], xB[16];
    const float4* xpA = (const float4*)(x + (long)(qbase + l) * D);
    const float4* xpB = (const float4*)(x + (long)(qbase + 64 + l) * D);
#pragma unroll
    for (int i = 0; i < 16; ++i) { xA[i] = xpA[i]; xB[i] = xpB[i]; }
    __syncthreads();
    const int code0 = __builtin_amdgcn_readfirstlane(w << 8);
    const float* ep0 = emb + (long)code0 * D;
    float bestA = 3.4e38f, bestB = 3.4e38f;
    int idxA = 0, idxB = 0;
#pragma unroll 1
    for (int g = 0; g < 256; ++g) {
        const float* ep = ep0 + g * D;
        f32x16 b0, b1, b2, b3;
        asm volatile(
            "s_load_dwordx16 %0, %4, 0x0\n\t"
            "s_load_dwordx16 %1, %4, 0x40\n\t"
            "s_load_dwordx16 %2, %4, 0x80\n\t"
            "s_load_dwordx16 %3, %4, 0xC0\n\t"
            "s_waitcnt lgkmcnt(0)"
            : "=s"(b0), "=s"(b1), "=s"(b2), "=s"(b3) : "s"(ep));
        float aA0 = 0.f, aA1 = 0.f, aA2 = 0.f, aA3 = 0.f;
        float aB0 = 0.f, aB1 = 0.f, aB2 = 0.f, aB3 = 0.f;
        FDO_CHUNK(b0, 0) FDO_CHUNK(b1, 1) FDO_CHUNK(b2, 2) FDO_CHUNK(b3, 3)
        float dotA = (aA0 + aA1) + (aA2 + aA3);
        float dotB = (aB0 + aB1) + (aB2 + aB3);
        float e2c = e2l[code0 + g];
        float sA = 0.5f * e2c - dotA;
        float sB = 0.5f * e2c - dotB;
        int code = code0 + g;
        bool lt;
        lt = sA < bestA; bestA = lt ? sA : bestA; idxA = lt ? code : idxA;
        lt = sB < bestB; bestB = lt ? sB : bestB; idxB = lt ? code : idxB;
    }
    sm_s[w * 128 + l] = bestA;      sm_c[w * 128 + l] = idxA;
    sm_s[w * 128 + 64 + l] = bestB; sm_c[w * 128 + 64 + l] = idxB;
    __syncthreads();
    if (tid < 128) {
        float bs = sm_s[tid]; int bc = sm_c[tid];
#pragma unroll
        for (int wv = 1; wv < 4; ++wv) {
            float s = sm_s[wv * 128 + tid]; int c = sm_c[wv * 128 + tid];
            if (s < bs) { bs = s; bc = c; }
        }
        const int q = qbase + tid;
        out[IDX_OUT_OFF + q] = (float)bc;
        const float4* eb = (const float4*)(emb + (long)bc * D);
        const float4* xq = (const float4*)(x + (long)q * D);
        float4* oq = (float4*)(out + (long)q * D);
        float lsum = 0.f;
#pragma unroll
        for (int i = 0; i < 16; ++i) {
            float4 e = eb[i]; float4 xx = xq[i];
            oq[i] = e;
            float dx = e.x - xx.x, dy = e.y - xx.y, dz = e.z - xx.z, dw = e.w - xx.w;
            lsum += dx * dx + dy * dy + dz * dz + dw * dw;
        }
#pragma unroll
        for (int o = 32; o > 0; o >>= 1) lsum += __shfl_down(lsum, o, 64);
        if ((tid & 63) == 0) atomicAdd(&out[LOSS_OFF], lsum * (0.25f / (float)NELEM));
    }
}

extern "C" void kernel_launch(void* const* d_in, const int* in_sizes, int n_in,
                              void* d_out, int out_size, void* d_ws, size_t ws_size,
                              hipStream_t stream) {
    const float* x   = (const float*)d_in[0];
    const float* emb = (const float*)d_in[1];
    float* out = (float*)d_out;
    char* ws = (char*)d_ws;

    if (ws_size < (size_t)WS_NEED) {           // fallback: proven R3 path
        float* e2 = (float*)ws;
        vq_e2f<<<4, 256, 0, stream>>>(emb, e2, out);
        vq_mainf<<<QTOTAL / 128, 256, 0, stream>>>(x, emb, e2, out);
        return;
    }

    float* e2    = (float*)(ws + WS_E2);
    ushort_t* B  = (ushort_t*)(ws + WS_B);
    u32* cnt     = (u32*)(ws + WS_CNT);
    int* list    = (int*)(ws + WS_LIST);

    vqk0<<<128, 256, 0, stream>>>(emb, (u32*)B, e2, cnt, out);
    vqk1<<<QTOTAL / 128, 512, 0, stream>>>(x, B, e2, emb, cnt, list, out);
    vqk2<<<256, 64, 0, stream>>>(x, emb, e2, list, cnt, out);
}